// Round 6
// baseline (4243.633 us; speedup 1.0000x reference)
//
#include <hip/hip_runtime.h>
#include <hip/hip_bf16.h>

// FP8Linear: emulated-fp8 quantize (scale=1) of x[M,K] and w[N,K], then
// out[M,N] = Xq @ Wq^T + bias, f32.
// Quantized values have <=4 significant bits -> exact in bf16.
// Pass 1: quantize f32 -> bf16 into d_ws.
// Pass 2: bf16 MFMA GEMM, 256x256 tile, BK=64, 8 waves (2Mx4N), 2-dbuf
// 128KB LDS. REGISTER staging: global->VGPR issued at P1 (3 phases of HBM
// cover), swizzled ds_write_b128 AFTER P4's MFMA cluster, lgkmcnt(0) before
// the publishing barrier.
// __launch_bounds__(512, 1): k=1 <=> 2 waves/EU <=> 256-VGPR unified budget.
// (R4's (512,2) meant 4 waves/EU -> 128 cap -> staged regs spilled to
// scratch: WRITE_SIZE 0.53->4.7GB. R5's amdgpu_waves_per_eu didn't take.)
// XOR-swizzled LDS, setprio MFMA clusters, XCD block swizzle.

typedef short bf16x8 __attribute__((ext_vector_type(8)));
typedef float f32x4 __attribute__((ext_vector_type(4)));

#define BM 256
#define BN 256
#define BK 64

__device__ __forceinline__ unsigned short quant1(float v) {
    float s = fminf(fmaxf(v, -448.0f), 448.0f);
    float e = floorf(log2f(fabsf(s) + 1e-10f));
    float m = exp2f(e - 3.0f);
    float q = rintf(s / m) * m;
    return (unsigned short)(__float_as_uint(q) >> 16);  // exact: <=4 sig bits
}

__global__ __launch_bounds__(256) void quant_kernel(
    const float4* __restrict__ in, ushort4* __restrict__ out, int n4) {
    int i = blockIdx.x * blockDim.x + threadIdx.x;
    if (i >= n4) return;
    float4 v = in[i];
    ushort4 r;
    r.x = quant1(v.x);
    r.y = quant1(v.y);
    r.z = quant1(v.z);
    r.w = quant1(v.w);
    out[i] = r;
}

// Swizzled fragment read: logical (row,col) -> lds[row*64 + (col ^ sw)],
// sw = (lane&7)<<3 (== (row&7)<<3 for all fragment rows: row = base16 + rl).
__device__ __forceinline__ bf16x8 frag_ld(const short* base, int row, int col, int sw) {
    return *(const bf16x8*)(base + (row << 6) + (col ^ sw));
}

__device__ __forceinline__ void load_af(bf16x8 (&af)[2][2], const short* Ab,
                                        int rbase, int kg, int sw) {
#pragma unroll
    for (int mi = 0; mi < 2; ++mi)
#pragma unroll
        for (int kk = 0; kk < 2; ++kk)
            af[mi][kk] = frag_ld(Ab, rbase + mi * 16, kk * 32 + kg, sw);
}

template <int MBASE>
__device__ __forceinline__ void mfma_quad(f32x4 (&acc)[8][4], const bf16x8 (&af)[2][2],
                                          const bf16x8 (&bfr)[4][2]) {
#pragma unroll
    for (int mi = 0; mi < 2; ++mi)
#pragma unroll
        for (int n = 0; n < 4; ++n)
#pragma unroll
            for (int kk = 0; kk < 2; ++kk)
                acc[MBASE + mi][n] = __builtin_amdgcn_mfma_f32_16x16x32_bf16(
                    af[mi][kk], bfr[n][kk], acc[MBASE + mi][n], 0, 0, 0);
}

#define LGKM0_SB                                         \
    asm volatile("s_waitcnt lgkmcnt(0)" ::: "memory");   \
    __builtin_amdgcn_sched_barrier(0)

// A: Xq [M][K], B: Wq [N][K] (bf16 as short), C: [M][N] f32
__global__ __launch_bounds__(512, 1) void gemm8p(
    const short* __restrict__ A, const short* __restrict__ B,
    const float* __restrict__ bias, float* __restrict__ C,
    int M, int N, int K) {
    extern __shared__ short lds[];  // 2 bufs x (A 16384 + B 16384) shorts = 128KB

    const int tid = threadIdx.x;
    const int lane = tid & 63;
    const int wave = tid >> 6;
    const int wr = wave >> 2;   // 0..1 -> 128 rows each
    const int wc = wave & 3;    // 0..3 -> 64 cols each

    // XCD-aware bijective block swizzle (nwg % 8 == 0)
    const int nwg = gridDim.x;
    const int per = nwg >> 3;
    const int bid = blockIdx.x;
    const int wg = (bid & 7) * per + (bid >> 3);
    const int mtiles = M / BM;
    const int bm = wg % mtiles;
    const int bn = wg / mtiles;

    const int arow0 = bm * BM, brow0 = bn * BN;
    const int NT = K / BK;

    const int rl = lane & 15;
    const int kg = (lane >> 4) << 3;
    const int sw = (lane & 7) << 3;
    const int arb = wr * 128 + rl;
    const int brb = wc * 64 + rl;

    const short* const Aglob = A + (size_t)arow0 * K;
    const short* const Bglob = B + (size_t)brow0 * K;

    // reg-staging addressing: chunk c covers row c*64+srow, cols scol..scol+7
    const int srow = tid >> 3;          // 0..63
    const int scol = (tid & 7) * 8;     // linear global col -> coalesced loads
    const int sdst = scol ^ ((srow & 7) << 3);  // swizzled LDS col

    f32x4 acc[8][4] = {};
    int4 ar[4], br[4];

    auto issue_loads = [&](int kt) {
#pragma unroll
        for (int c = 0; c < 4; ++c)
            ar[c] = *(const int4*)(Aglob + (size_t)(c * 64 + srow) * K + kt + scol);
#pragma unroll
        for (int c = 0; c < 4; ++c)
            br[c] = *(const int4*)(Bglob + (size_t)(c * 64 + srow) * K + kt + scol);
    };
    auto write_lds = [&](short* An, short* Bn) {
#pragma unroll
        for (int c = 0; c < 4; ++c)
            *(int4*)(An + (c * 64 + srow) * 64 + sdst) = ar[c];
#pragma unroll
        for (int c = 0; c < 4; ++c)
            *(int4*)(Bn + (c * 64 + srow) * 64 + sdst) = br[c];
    };

    // ---- prologue: stage tile 0 into buf 0 via regs
    issue_loads(0);
    write_lds(lds, lds + 16384);
    LGKM0_SB;
    __builtin_amdgcn_s_barrier();

    for (int t = 0; t < NT; ++t) {
        const int cur = t & 1;
        const short* Ab = lds + cur * 32768;
        const short* Bb = Ab + 16384;
        short* An = lds + (cur ^ 1) * 32768;
        short* Bn = An + 16384;
        const bool pf = (t + 1 < NT);

        bf16x8 bfr[4][2];
        bf16x8 af[2][2];

        // ---- P1: issue next-tile global loads; read all B frags + A m0-1
        if (pf) issue_loads((t + 1) * BK);
#pragma unroll
        for (int n = 0; n < 4; ++n)
#pragma unroll
            for (int kk = 0; kk < 2; ++kk)
                bfr[n][kk] = frag_ld(Bb, brb + n * 16, kk * 32 + kg, sw);
        load_af(af, Ab, arb + 0 * 16, kg, sw);
        __builtin_amdgcn_s_barrier();
        LGKM0_SB;
        __builtin_amdgcn_s_setprio(1);
        mfma_quad<0>(acc, af, bfr);
        __builtin_amdgcn_s_setprio(0);
        __builtin_amdgcn_s_barrier();

        // ---- P2: A m2-3
        load_af(af, Ab, arb + 2 * 16, kg, sw);
        __builtin_amdgcn_s_barrier();
        LGKM0_SB;
        __builtin_amdgcn_s_setprio(1);
        mfma_quad<2>(acc, af, bfr);
        __builtin_amdgcn_s_setprio(0);
        __builtin_amdgcn_s_barrier();

        // ---- P3: A m4-5
        load_af(af, Ab, arb + 4 * 16, kg, sw);
        __builtin_amdgcn_s_barrier();
        LGKM0_SB;
        __builtin_amdgcn_s_setprio(1);
        mfma_quad<4>(acc, af, bfr);
        __builtin_amdgcn_s_setprio(0);
        __builtin_amdgcn_s_barrier();

        // ---- P4: A m6-7; MFMA first; then write staged regs into other buf
        //          (compiler inserts precise vmcnt before the writes; loads
        //          have had ~3 phases to land). lgkmcnt(0) publishes writes
        //          across the closing barrier for next P1's readers.
        load_af(af, Ab, arb + 6 * 16, kg, sw);
        __builtin_amdgcn_s_barrier();
        LGKM0_SB;
        __builtin_amdgcn_s_setprio(1);
        mfma_quad<6>(acc, af, bfr);
        __builtin_amdgcn_s_setprio(0);
        if (pf) write_lds(An, Bn);
        asm volatile("s_waitcnt lgkmcnt(0)" ::: "memory");
        __builtin_amdgcn_s_barrier();
    }

    // epilogue: D row = (lane>>4)*4 + j (A side), col = lane&15 (B side)
    const int rg = (lane >> 4) * 4;
#pragma unroll
    for (int n = 0; n < 4; ++n) {
        int col = brow0 + wc * 64 + n * 16 + rl;
        float bv = bias[col];
#pragma unroll
        for (int m = 0; m < 8; ++m) {
            int rowb = arow0 + wr * 128 + m * 16 + rg;
#pragma unroll
            for (int j = 0; j < 4; ++j)
                C[(size_t)(rowb + j) * N + col] = acc[m][n][j] + bv;
        }
    }
}

extern "C" void kernel_launch(void* const* d_in, const int* in_sizes, int n_in,
                              void* d_out, int out_size, void* d_ws, size_t ws_size,
                              hipStream_t stream) {
    const float* x = (const float*)d_in[0];     // [M,K]
    const float* w = (const float*)d_in[1];     // [N,K]
    const float* bias = (const float*)d_in[2];  // [N]
    float* out = (float*)d_out;

    const int N = in_sizes[2];                 // 16384
    const int K = in_sizes[1] / N;             // 4096
    const int M = in_sizes[0] / K;             // 8192

    short* xq = (short*)d_ws;
    short* wq = xq + (size_t)M * K;

    int nx4 = M * K / 4;
    int nw4 = N * K / 4;
    quant_kernel<<<(nx4 + 255) / 256, 256, 0, stream>>>(
        (const float4*)x, (ushort4*)xq, nx4);
    quant_kernel<<<(nw4 + 255) / 256, 256, 0, stream>>>(
        (const float4*)w, (ushort4*)wq, nw4);

    hipFuncSetAttribute((const void*)gemm8p,
                        hipFuncAttributeMaxDynamicSharedMemorySize, 131072);

    int nwg = (M / BM) * (N / BN);  // 32*64 = 2048, %8==0
    gemm8p<<<nwg, 512, 131072, stream>>>(
        (const short*)xq, (const short*)wq, bias, out, M, N, K);
}

// Round 7
// 2640.350 us; speedup vs baseline: 1.6072x; 1.6072x over previous
//
#include <hip/hip_runtime.h>
#include <hip/hip_bf16.h>

// FP8Linear: emulated-fp8 quantize (scale=1) of x[M,K] and w[N,K], then
// out[M,N] = Xq @ Wq^T + bias, f32.
// Quantized values have <=4 significant bits -> exact in bf16.
// Pass 1: quantize f32 -> bf16 into d_ws.
// Pass 2: bf16 MFMA GEMM, 256x256 tile, BK=64, 8 waves (2Mx4N), 2-dbuf
// 128KB LDS, 8-phase/2-K-tile counted-vmcnt schedule (vmcnt(6), never 0
// mid-loop). ALL fragment reads are inline-asm ds_read_b128 (opaque to the
// compiler's waitcnt pass -> it cannot insert vmcnt(0) drains for
// global_load_lds aliasing) and ALL waitcnt asms have NO memory clobber
// (a "memory" clobber makes the asm mayLoad -> compiler pre-drains vmcnt).
// Ordering is enforced by sched_barrier(0) fences (rule #18).
// XOR-swizzled LDS (pre-swizzled global src), setprio, XCD block swizzle.

typedef short bf16x8 __attribute__((ext_vector_type(8)));
typedef float f32x4 __attribute__((ext_vector_type(4)));

#define BM 256
#define BN 256
#define BK 64

__device__ __forceinline__ unsigned short quant1(float v) {
    float s = fminf(fmaxf(v, -448.0f), 448.0f);
    float e = floorf(log2f(fabsf(s) + 1e-10f));
    float m = exp2f(e - 3.0f);
    float q = rintf(s / m) * m;
    return (unsigned short)(__float_as_uint(q) >> 16);  // exact: <=4 sig bits
}

__global__ __launch_bounds__(256) void quant_kernel(
    const float4* __restrict__ in, ushort4* __restrict__ out, int n4) {
    int i = blockIdx.x * blockDim.x + threadIdx.x;
    if (i >= n4) return;
    float4 v = in[i];
    ushort4 r;
    r.x = quant1(v.x);
    r.y = quant1(v.y);
    r.z = quant1(v.z);
    r.w = quant1(v.w);
    out[i] = r;
}

__device__ __forceinline__ void gload_lds16(const void* g, void* l) {
    __builtin_amdgcn_global_load_lds(
        (const __attribute__((address_space(1))) void*)g,
        (__attribute__((address_space(3))) void*)l,
        16, 0, 0);
}

// Opaque LDS read: compiler's waitcnt pass cannot see this as an LDS access,
// so it cannot insert conservative vmcnt(0) drains before it. Completion is
// enforced ONLY by our explicit lgkmcnt(0)+sched_barrier fences.
__device__ __forceinline__ bf16x8 ds_read128(const short* p) {
    bf16x8 r;
    asm volatile("ds_read_b128 %0, %1"
                 : "=&v"(r)
                 : "v"((const __attribute__((address_space(3))) short*)p));
    return r;
}

// Swizzled fragment read: logical (row,col) -> lds[row*64 + (col ^ sw)].
__device__ __forceinline__ bf16x8 frag_ld(const short* base, int row, int col, int sw) {
    return ds_read128(base + (row << 6) + (col ^ sw));
}

template <int MH, int NH>
__device__ __forceinline__ void mfma_phase(f32x4 (&acc)[8][4], const bf16x8 (&af)[4][2],
                                           const bf16x8 (&bf)[2][2][2]) {
#pragma unroll
    for (int mi = 0; mi < 4; ++mi)
#pragma unroll
        for (int n = 0; n < 2; ++n)
#pragma unroll
            for (int kk = 0; kk < 2; ++kk)
                acc[MH * 4 + mi][NH * 2 + n] = __builtin_amdgcn_mfma_f32_16x16x32_bf16(
                    af[mi][kk], bf[NH][n][kk], acc[MH * 4 + mi][NH * 2 + n], 0, 0, 0);
}

// Waits WITHOUT memory clobber (clobber => mayLoad => compiler pre-drains
// vmcnt before the asm). sched_barrier(0) pins code motion instead.
#define WAIT_LGKM0                              \
    asm volatile("s_waitcnt lgkmcnt(0)");       \
    __builtin_amdgcn_sched_barrier(0)
#define WAIT_VM(n)                                   \
    __builtin_amdgcn_sched_barrier(0);               \
    asm volatile("s_waitcnt vmcnt(" #n ")");         \
    __builtin_amdgcn_sched_barrier(0)

// A: Xq [M][K], B: Wq [N][K] (bf16 as short), C: [M][N] f32
__global__ __launch_bounds__(512) void gemm8p(
    const short* __restrict__ A, const short* __restrict__ B,
    const float* __restrict__ bias, float* __restrict__ C,
    int M, int N, int K) {
    extern __shared__ short lds[];
    short* const ldsA0 = lds;
    short* const ldsB0 = lds + 16384;
    short* const ldsA1 = lds + 32768;
    short* const ldsB1 = lds + 49152;

    const int tid = threadIdx.x;
    const int lane = tid & 63;
    const int wave = tid >> 6;
    const int wr = wave >> 2;   // 0..1 -> 128 rows each
    const int wc = wave & 3;    // 0..3 -> 64 cols each

    // XCD-aware bijective block swizzle (nwg % 8 == 0)
    const int nwg = gridDim.x;
    const int per = nwg >> 3;
    const int bid = blockIdx.x;
    const int wg = (bid & 7) * per + (bid >> 3);
    const int mtiles = M / BM;
    const int bm = wg % mtiles;
    const int bn = wg / mtiles;

    const int arow0 = bm * BM, brow0 = bn * BN;
    const int NT = K / BK;  // 64, even

    const int rl = lane & 15;
    const int kg = (lane >> 4) << 3;
    const int sw = (lane & 7) << 3;
    const int arb = wr * 128 + rl;
    const int brb = wc * 64 + rl;

    const short* const Aglob = A + (size_t)arow0 * K;
    const short* const Bglob = B + (size_t)brow0 * K;

    // staging: half-tile = 128 rows x 64 cols; 2 x gload_lds16 per thread.
    // LDS dest linear; global source pre-swizzled (both-sides rule).
    const int col0 = (((tid & 7) ^ ((tid >> 3) & 7)) << 3);
    const size_t tsrc = (size_t)(tid >> 3) * K + col0;
    const int tdst = tid * 8;

    auto stage = [&](const short* Gp, short* Lp, int region, int kt) {
#pragma unroll
        for (int c = 0; c < 2; ++c) {
            gload_lds16(Gp + (size_t)(region * 128 + c * 64) * K + kt + tsrc,
                        Lp + region * 8192 + c * 4096 + tdst);
        }
    };

    f32x4 acc[8][4] = {};
    bf16x8 af[4][2];
    bf16x8 bf[2][2][2];

    auto readAF = [&](const short* Ab, int mh) {
#pragma unroll
        for (int mi = 0; mi < 4; ++mi)
#pragma unroll
            for (int kk = 0; kk < 2; ++kk)
                af[mi][kk] = frag_ld(Ab, arb + (mh * 4 + mi) * 16, kk * 32 + kg, sw);
    };
    auto readBF = [&](const short* Bb, int nh) {
#pragma unroll
        for (int n = 0; n < 2; ++n)
#pragma unroll
            for (int kk = 0; kk < 2; ++kk)
                bf[nh][n][kk] = frag_ld(Bb, brb + (nh * 2 + n) * 16, kk * 32 + kg, sw);
    };

    // ---- prologue: tile0 full -> buf0; tile1 {B-lo, B-hi, A-lo} -> buf1
    stage(Aglob, ldsA0, 0, 0);
    stage(Aglob, ldsA0, 1, 0);
    stage(Bglob, ldsB0, 0, 0);
    stage(Bglob, ldsB0, 1, 0);
    stage(Bglob, ldsB1, 0, BK);
    stage(Bglob, ldsB1, 1, BK);
    stage(Aglob, ldsA1, 0, BK);
    WAIT_VM(6);  // tile0 landed; 3 half-tiles in flight
    __builtin_amdgcn_s_barrier();

    for (int t = 0; t < NT; t += 2) {
        const int kt1 = (t + 1) * BK, kt2 = (t + 2) * BK, kt3 = (t + 3) * BK;
        const bool p2 = (t + 2 < NT), p3 = (t + 3 < NT);

        // P1: reads bf(nh0)+af(mh0) from buf0; stage A-hi(t+1)->buf1
        readBF(ldsB0, 0);
        readAF(ldsA0, 0);
        stage(Aglob, ldsA1, 1, kt1);
        __builtin_amdgcn_s_barrier();
        WAIT_LGKM0;
        __builtin_amdgcn_s_setprio(1);
        mfma_phase<0, 0>(acc, af, bf);
        __builtin_amdgcn_s_setprio(0);
        __builtin_amdgcn_s_barrier();

        // P2: reads bf(nh1) from buf0
        readBF(ldsB0, 1);
        __builtin_amdgcn_s_barrier();
        WAIT_LGKM0;
        __builtin_amdgcn_s_setprio(1);
        mfma_phase<0, 1>(acc, af, bf);
        __builtin_amdgcn_s_setprio(0);
        __builtin_amdgcn_s_barrier();

        // P3: reads af(mh1) from buf0; stage B-lo(t+2)->buf0 (B0 retired @P2)
        readAF(ldsA0, 1);
        if (p2) stage(Bglob, ldsB0, 0, kt2);
        __builtin_amdgcn_s_barrier();
        WAIT_LGKM0;
        __builtin_amdgcn_s_setprio(1);
        mfma_phase<1, 0>(acc, af, bf);
        __builtin_amdgcn_s_setprio(0);
        __builtin_amdgcn_s_barrier();

        // P4: stage B-hi(t+2)+A-lo(t+2)->buf0 (A0 retired @P3);
        //     counted vmcnt(6) forces tile t+1 landed before P5 reads buf1.
        if (p2) {
            stage(Bglob, ldsB0, 1, kt2);
            stage(Aglob, ldsA0, 0, kt2);
        }
        __builtin_amdgcn_s_barrier();
        __builtin_amdgcn_s_setprio(1);
        mfma_phase<1, 1>(acc, af, bf);
        __builtin_amdgcn_s_setprio(0);
        if (p2) {
            WAIT_VM(6);
        } else {
            WAIT_VM(0);  // tail: force A-hi(t+1)
        }
        __builtin_amdgcn_s_barrier();

        // P5: reads bf(nh0)+af(mh0) from buf1; stage A-hi(t+2)->buf0
        readBF(ldsB1, 0);
        readAF(ldsA1, 0);
        if (p2) stage(Aglob, ldsA0, 1, kt2);
        __builtin_amdgcn_s_barrier();
        WAIT_LGKM0;
        __builtin_amdgcn_s_setprio(1);
        mfma_phase<0, 0>(acc, af, bf);
        __builtin_amdgcn_s_setprio(0);
        __builtin_amdgcn_s_barrier();

        // P6: reads bf(nh1) from buf1
        readBF(ldsB1, 1);
        __builtin_amdgcn_s_barrier();
        WAIT_LGKM0;
        __builtin_amdgcn_s_setprio(1);
        mfma_phase<0, 1>(acc, af, bf);
        __builtin_amdgcn_s_setprio(0);
        __builtin_amdgcn_s_barrier();

        // P7: reads af(mh1) from buf1; stage B-lo(t+3)->buf1 (B1 retired @P6)
        readAF(ldsA1, 1);
        if (p3) stage(Bglob, ldsB1, 0, kt3);
        __builtin_amdgcn_s_barrier();
        WAIT_LGKM0;
        __builtin_amdgcn_s_setprio(1);
        mfma_phase<1, 0>(acc, af, bf);
        __builtin_amdgcn_s_setprio(0);
        __builtin_amdgcn_s_barrier();

        // P8: stage B-hi(t+3)+A-lo(t+3)->buf1 (A1 retired @P7);
        //     vmcnt(6) forces tile t+2 landed before next P1 reads buf0.
        if (p3) {
            stage(Bglob, ldsB1, 1, kt3);
            stage(Aglob, ldsA1, 0, kt3);
        }
        __builtin_amdgcn_s_barrier();
        __builtin_amdgcn_s_setprio(1);
        mfma_phase<1, 1>(acc, af, bf);
        __builtin_amdgcn_s_setprio(0);
        WAIT_VM(6);
        __builtin_amdgcn_s_barrier();
    }

    // epilogue: D row = (lane>>4)*4 + j (A side), col = lane&15 (B side)
    const int rg = (lane >> 4) * 4;
#pragma unroll
    for (int n = 0; n < 4; ++n) {
        int col = brow0 + wc * 64 + n * 16 + rl;
        float bv = bias[col];
#pragma unroll
        for (int m = 0; m < 8; ++m) {
            int rowb = arow0 + wr * 128 + m * 16 + rg;
#pragma unroll
            for (int j = 0; j < 4; ++j)
                C[(size_t)(rowb + j) * N + col] = acc[m][n][j] + bv;
        }
    }
}

extern "C" void kernel_launch(void* const* d_in, const int* in_sizes, int n_in,
                              void* d_out, int out_size, void* d_ws, size_t ws_size,
                              hipStream_t stream) {
    const float* x = (const float*)d_in[0];     // [M,K]
    const float* w = (const float*)d_in[1];     // [N,K]
    const float* bias = (const float*)d_in[2];  // [N]
    float* out = (float*)d_out;

    const int N = in_sizes[2];                 // 16384
    const int K = in_sizes[1] / N;             // 4096
    const int M = in_sizes[0] / K;             // 8192

    short* xq = (short*)d_ws;
    short* wq = xq + (size_t)M * K;

    int nx4 = M * K / 4;
    int nw4 = N * K / 4;
    quant_kernel<<<(nx4 + 255) / 256, 256, 0, stream>>>(
        (const float4*)x, (ushort4*)xq, nx4);
    quant_kernel<<<(nw4 + 255) / 256, 256, 0, stream>>>(
        (const float4*)w, (ushort4*)wq, nw4);

    hipFuncSetAttribute((const void*)gemm8p,
                        hipFuncAttributeMaxDynamicSharedMemorySize, 131072);

    int nwg = (M / BM) * (N / BN);  // 32*64 = 2048, %8==0
    gemm8p<<<nwg, 512, 131072, stream>>>(
        (const short*)xq, (const short*)wq, bias, out, M, N, K);
}

// Round 8
// 1342.916 us; speedup vs baseline: 3.1600x; 1.9661x over previous
//
#include <hip/hip_runtime.h>
#include <hip/hip_bf16.h>

// FP8Linear: emulated-fp8 quantize (scale=1) of x[M,K] and w[N,K], then
// out[M,N] = Xq @ Wq^T + bias, f32.
// Quantized values have <=4 significant bits -> exact in bf16.
// Pass 1: quantize f32 -> bf16 into d_ws.
// Pass 2: bf16 MFMA GEMM, 256x256 tile, BK=64, 8 waves (2Mx4N), 2-dbuf
// 128KB LDS, ONE __syncthreads per K-tile. Rationale (R2-R7 post-mortems):
// at 2 waves/SIMD the kernel is LDS-port-bound (~2300 cyc/K-tile of ds_read
// traffic vs 620 cyc MFMA); multi-phase lockstep barriers (8/K-tile) kept all
// waves re-converging and cost 2.4x over the LDS floor. Single-barrier lets
// the 8 waves self-stagger on the LDS port; the sync's implicit vmcnt(0)
// drains DMAs issued a full tile earlier (~3000 cyc cover = free); compiler
// inserts precise lgkmcnt for ds_read->MFMA (m97-verified behavior).
// XOR-swizzled LDS (pre-swizzled global src + swizzled reads), XCD swizzle.

typedef short bf16x8 __attribute__((ext_vector_type(8)));
typedef float f32x4 __attribute__((ext_vector_type(4)));

#define BM 256
#define BN 256
#define BK 64

__device__ __forceinline__ unsigned short quant1(float v) {
    float s = fminf(fmaxf(v, -448.0f), 448.0f);
    float e = floorf(log2f(fabsf(s) + 1e-10f));
    float m = exp2f(e - 3.0f);
    float q = rintf(s / m) * m;
    return (unsigned short)(__float_as_uint(q) >> 16);  // exact: <=4 sig bits
}

__global__ __launch_bounds__(256) void quant_kernel(
    const float4* __restrict__ in, ushort4* __restrict__ out, int n4) {
    int i = blockIdx.x * blockDim.x + threadIdx.x;
    if (i >= n4) return;
    float4 v = in[i];
    ushort4 r;
    r.x = quant1(v.x);
    r.y = quant1(v.y);
    r.z = quant1(v.z);
    r.w = quant1(v.w);
    out[i] = r;
}

__device__ __forceinline__ void gload_lds16(const void* g, void* l) {
    __builtin_amdgcn_global_load_lds(
        (const __attribute__((address_space(1))) void*)g,
        (__attribute__((address_space(3))) void*)l,
        16, 0, 0);
}

// Swizzled fragment read: logical (row,col) -> lds[row*64 + (col ^ sw)],
// sw = (lane&7)<<3 (== (row&7)<<3 for all fragment rows: row = base16 + rl).
__device__ __forceinline__ bf16x8 frag_ld(const short* base, int row, int col, int sw) {
    return *(const bf16x8*)(base + (row << 6) + (col ^ sw));
}

// A: Xq [M][K], B: Wq [N][K] (bf16 as short), C: [M][N] f32
__global__ __launch_bounds__(512) void gemm1b(
    const short* __restrict__ A, const short* __restrict__ B,
    const float* __restrict__ bias, float* __restrict__ C,
    int M, int N, int K) {
    extern __shared__ short lds[];  // 2 bufs x (A 16384 + B 16384) shorts = 128KB

    const int tid = threadIdx.x;
    const int lane = tid & 63;
    const int wave = tid >> 6;
    const int wr = wave >> 2;   // 0..1 -> 128 rows each
    const int wc = wave & 3;    // 0..3 -> 64 cols each

    // XCD-aware bijective block swizzle (nwg % 8 == 0)
    const int nwg = gridDim.x;
    const int per = nwg >> 3;
    const int bid = blockIdx.x;
    const int wg = (bid & 7) * per + (bid >> 3);
    const int mtiles = M / BM;
    const int bm = wg % mtiles;
    const int bn = wg / mtiles;

    const int arow0 = bm * BM, brow0 = bn * BN;
    const int NT = K / BK;

    const int rl = lane & 15;
    const int kg = (lane >> 4) << 3;
    const int sw = (lane & 7) << 3;
    const int arb = wr * 128 + rl;
    const int brb = wc * 64 + rl;

    const short* const Aglob = A + (size_t)arow0 * K;
    const short* const Bglob = B + (size_t)brow0 * K;

    // staging: per thread 4+4 x 16B chunks; LDS dest linear (DMA constraint),
    // global source pre-swizzled (both-sides rule).
    const int col0 = (((tid & 7) ^ ((tid >> 3) & 7)) << 3);
    const size_t tsrc = (size_t)(tid >> 3) * K + col0;
    const int tdst = tid * 8;

    auto stage_tiles = [&](short* An, short* Bn, int kt) {
#pragma unroll
        for (int c = 0; c < 4; ++c)
            gload_lds16(Aglob + (size_t)(c * 64) * K + kt + tsrc,
                        An + c * 4096 + tdst);
#pragma unroll
        for (int c = 0; c < 4; ++c)
            gload_lds16(Bglob + (size_t)(c * 64) * K + kt + tsrc,
                        Bn + c * 4096 + tdst);
    };

    f32x4 acc[8][4] = {};

    // ---- prologue: stage tile 0 into buf 0
    stage_tiles(lds, lds + 16384, 0);
    __syncthreads();  // vmcnt(0) drain + barrier: tile 0 visible to all

    for (int t = 0; t < NT; ++t) {
        const int cur = t & 1;
        const short* Ab = lds + cur * 32768;
        const short* Bb = Ab + 16384;
        short* An = lds + (cur ^ 1) * 32768;
        short* Bn = An + 16384;

        // issue next tile's DMA loads first: full K-tile of latency cover
        if (t + 1 < NT) stage_tiles(An, Bn, (t + 1) * BK);

        // B fragments (reused across both m-halves)
        bf16x8 bfr[4][2];
#pragma unroll
        for (int n = 0; n < 4; ++n)
#pragma unroll
            for (int kk = 0; kk < 2; ++kk)
                bfr[n][kk] = frag_ld(Bb, brb + n * 16, kk * 32 + kg, sw);

        // m-half 0: frags m0-3, 32 MFMAs
        {
            bf16x8 af[4][2];
#pragma unroll
            for (int mi = 0; mi < 4; ++mi)
#pragma unroll
                for (int kk = 0; kk < 2; ++kk)
                    af[mi][kk] = frag_ld(Ab, arb + mi * 16, kk * 32 + kg, sw);
#pragma unroll
            for (int mi = 0; mi < 4; ++mi)
#pragma unroll
                for (int n = 0; n < 4; ++n)
#pragma unroll
                    for (int kk = 0; kk < 2; ++kk)
                        acc[mi][n] = __builtin_amdgcn_mfma_f32_16x16x32_bf16(
                            af[mi][kk], bfr[n][kk], acc[mi][n], 0, 0, 0);
        }
        // m-half 1: frags m4-7, 32 MFMAs
        {
            bf16x8 af[4][2];
#pragma unroll
            for (int mi = 0; mi < 4; ++mi)
#pragma unroll
                for (int kk = 0; kk < 2; ++kk)
                    af[mi][kk] = frag_ld(Ab, arb + (4 + mi) * 16, kk * 32 + kg, sw);
#pragma unroll
            for (int mi = 0; mi < 4; ++mi)
#pragma unroll
                for (int n = 0; n < 4; ++n)
#pragma unroll
                    for (int kk = 0; kk < 2; ++kk)
                        acc[4 + mi][n] = __builtin_amdgcn_mfma_f32_16x16x32_bf16(
                            af[mi][kk], bfr[n][kk], acc[4 + mi][n], 0, 0, 0);
        }

        // single per-tile sync: drains my DMAs (issued ~full tile ago) and
        // my ds_reads (already consumed), then publishes buffers for t+1.
        __syncthreads();
    }

    // epilogue: D row = (lane>>4)*4 + j (A side), col = lane&15 (B side)
    const int rg = (lane >> 4) * 4;
#pragma unroll
    for (int n = 0; n < 4; ++n) {
        int col = brow0 + wc * 64 + n * 16 + rl;
        float bv = bias[col];
#pragma unroll
        for (int m = 0; m < 8; ++m) {
            int rowb = arow0 + wr * 128 + m * 16 + rg;
#pragma unroll
            for (int j = 0; j < 4; ++j)
                C[(size_t)(rowb + j) * N + col] = acc[m][n][j] + bv;
        }
    }
}

extern "C" void kernel_launch(void* const* d_in, const int* in_sizes, int n_in,
                              void* d_out, int out_size, void* d_ws, size_t ws_size,
                              hipStream_t stream) {
    const float* x = (const float*)d_in[0];     // [M,K]
    const float* w = (const float*)d_in[1];     // [N,K]
    const float* bias = (const float*)d_in[2];  // [N]
    float* out = (float*)d_out;

    const int N = in_sizes[2];                 // 16384
    const int K = in_sizes[1] / N;             // 4096
    const int M = in_sizes[0] / K;             // 8192

    short* xq = (short*)d_ws;
    short* wq = xq + (size_t)M * K;

    int nx4 = M * K / 4;
    int nw4 = N * K / 4;
    quant_kernel<<<(nx4 + 255) / 256, 256, 0, stream>>>(
        (const float4*)x, (ushort4*)xq, nx4);
    quant_kernel<<<(nw4 + 255) / 256, 256, 0, stream>>>(
        (const float4*)w, (ushort4*)wq, nw4);

    hipFuncSetAttribute((const void*)gemm1b,
                        hipFuncAttributeMaxDynamicSharedMemorySize, 131072);

    int nwg = (M / BM) * (N / BN);  // 32*64 = 2048, %8==0
    gemm1b<<<nwg, 512, 131072, stream>>>(
        (const short*)xq, (const short*)wq, bias, out, M, N, K);
}

// Round 9
// 900.906 us; speedup vs baseline: 4.7104x; 1.4906x over previous
//
#include <hip/hip_runtime.h>
#include <hip/hip_bf16.h>

// FP8Linear: out = Xq @ Wq^T + bias. Reference quantize (scale=1) == RNE
// conversion to OCP e4m3fn (4 sig bits, ties-even, clip +-448 = e4m3 max),
// except subnormal-grid coarsening. x stored as e4m3(x) (error ~1e-3 total);
// w stored as e4m3(w * 2^6) with MFMA B-scale 2^-6 (e8m0 byte 121) so all
// |w|>=2^-12 quantize EXACTLY; residual error ~1e-3 << 0.115 threshold.
// GEMM: proven m145/m148 configuration (learn_hip, refcheck'd, 1628 TF):
// 128x128 tile, 4 waves (2x2, 64x64 each), BK=128 = one
// mfma_scale_f32_16x16x128_f8f6f4 k-step, single 32KB LDS buffer, m97
// 2-barrier loop, ~3 blocks/CU (TLP hides the staging drain),
// global_load_lds width 16 with pre-swizzled source, XOR-swizzled reads
// (even bank distribution), XCD-aware block swizzle.

typedef int i32x4 __attribute__((ext_vector_type(4)));
typedef int i32x8 __attribute__((ext_vector_type(8)));
typedef float f32x4 __attribute__((ext_vector_type(4)));

#define BM 128
#define BN 128
#define BK 128

// clip to +-448, scale (1 or 64), RNE-encode 8 f32 -> 8 e4m3 bytes.
__global__ __launch_bounds__(256) void quant8(
    const float4* __restrict__ in, int2* __restrict__ out, int n8, float scale) {
    int i = blockIdx.x * blockDim.x + threadIdx.x;
    if (i >= n8) return;
    float4 a = in[i * 2];
    float4 b = in[i * 2 + 1];
    float c0 = fminf(fmaxf(a.x, -448.f), 448.f) * scale;
    float c1 = fminf(fmaxf(a.y, -448.f), 448.f) * scale;
    float c2 = fminf(fmaxf(a.z, -448.f), 448.f) * scale;
    float c3 = fminf(fmaxf(a.w, -448.f), 448.f) * scale;
    float c4 = fminf(fmaxf(b.x, -448.f), 448.f) * scale;
    float c5 = fminf(fmaxf(b.y, -448.f), 448.f) * scale;
    float c6 = fminf(fmaxf(b.z, -448.f), 448.f) * scale;
    float c7 = fminf(fmaxf(b.w, -448.f), 448.f) * scale;
    int lo = __builtin_amdgcn_cvt_pk_fp8_f32(c0, c1, 0, false);
    lo = __builtin_amdgcn_cvt_pk_fp8_f32(c2, c3, lo, true);
    int hi = __builtin_amdgcn_cvt_pk_fp8_f32(c4, c5, 0, false);
    hi = __builtin_amdgcn_cvt_pk_fp8_f32(c6, c7, hi, true);
    out[i] = make_int2(lo, hi);
}

__device__ __forceinline__ void gload_lds16(const void* g, void* l) {
    __builtin_amdgcn_global_load_lds(
        (const __attribute__((address_space(1))) void*)g,
        (__attribute__((address_space(3))) void*)l,
        16, 0, 0);
}

// Read one lane's 32-byte k-block (logical cols [g*32, g*32+32)) of `row`
// from a swizzled [128][128B] LDS tile. LDS[r][c] holds G[r][c ^ sw(r)],
// sw(r) = (r&7)<<4, so logical col cl lives at LDS col cl ^ sw(r).
__device__ __forceinline__ i32x8 frag32(const unsigned char* base, int row, int g) {
    const int sw = (row & 7) << 4;
    const unsigned char* p = base + row * 128;
    i32x4 lo = *(const i32x4*)(p + ((g * 32) ^ sw));
    i32x4 hi = *(const i32x4*)(p + ((g * 32 + 16) ^ sw));
    i32x8 r;
    r[0] = lo[0]; r[1] = lo[1]; r[2] = lo[2]; r[3] = lo[3];
    r[4] = hi[0]; r[5] = hi[1]; r[6] = hi[2]; r[7] = hi[3];
    return r;
}

// A: Xq8 [M][K] e4m3, B: Wq8 [N][K] e4m3 (pre-scaled by 2^6), C: [M][N] f32
__global__ __launch_bounds__(256, 3) void gemm_fp8(
    const unsigned char* __restrict__ A, const unsigned char* __restrict__ B,
    const float* __restrict__ bias, float* __restrict__ C,
    int M, int N, int K) {
    __shared__ unsigned char lA[BM * BK];  // 16 KB
    __shared__ unsigned char lB[BN * BK];  // 16 KB

    const int tid = threadIdx.x;
    const int lane = tid & 63;
    const int wave = tid >> 6;
    const int wr = wave >> 1;  // 2x2 wave grid, 64x64 output each
    const int wc = wave & 1;

    // XCD-aware bijective block swizzle (nwg % 8 == 0)
    const int nwg = gridDim.x;
    const int per = nwg >> 3;
    const int bid = blockIdx.x;
    const int wg = (bid & 7) * per + (bid >> 3);
    const int mtiles = M / BM;
    const int bm = wg % mtiles;
    const int bn = wg / mtiles;

    const int arow0 = bm * BM, bcol0 = bn * BN;
    const int NT = K / BK;  // 32

    const int rl = lane & 15;    // fragment row-within-16
    const int g = lane >> 4;     // k-group (32 bytes each)

    const unsigned char* const Ag = A + (size_t)arow0 * K;
    const unsigned char* const Bg = B + (size_t)bcol0 * K;

    // staging: thread t writes LDS bytes [t*16,(t+1)*16) of each 4KB chunk;
    // LDS dest linear (DMA constraint), global source pre-swizzled.
    const int srow = tid >> 3;                       // row within 32-row chunk
    const int ssrc_col = ((tid & 7) * 16) ^ (((tid >> 3) & 7) << 4);
    const int sdst = tid * 16;

    f32x4 acc[4][4] = {};

    for (int t = 0; t < NT; ++t) {
        const int kt = t * BK;
#pragma unroll
        for (int i = 0; i < 4; ++i)
            gload_lds16(Ag + (size_t)(i * 32 + srow) * K + kt + ssrc_col,
                        lA + i * 4096 + sdst);
#pragma unroll
        for (int i = 0; i < 4; ++i)
            gload_lds16(Bg + (size_t)(i * 32 + srow) * K + kt + ssrc_col,
                        lB + i * 4096 + sdst);
        __syncthreads();  // implicit vmcnt(0): tile landed, visible to all

        i32x8 bf[4];
#pragma unroll
        for (int n = 0; n < 4; ++n)
            bf[n] = frag32(lB, wc * 64 + n * 16 + rl, g);
#pragma unroll
        for (int m = 0; m < 4; ++m) {
            i32x8 af = frag32(lA, wr * 64 + m * 16 + rl, g);
#pragma unroll
            for (int n = 0; n < 4; ++n)
                acc[m][n] = __builtin_amdgcn_mfma_scale_f32_16x16x128_f8f6f4(
                    af, bf[n], acc[m][n],
                    0, 0,                 // cbsz=fp8(e4m3), blgp=fp8(e4m3)
                    0, 0x7F7F7F7F,        // A scale: 2^0
                    0, 0x79797979);       // B scale: 2^-6 (undo w*2^6)
        }
        __syncthreads();  // protect buffer before next tile's DMA
    }

    // epilogue: D row = (lane>>4)*4 + j (A side), col = lane&15 (B side)
    const int rg = (lane >> 4) * 4;
#pragma unroll
    for (int n = 0; n < 4; ++n) {
        int col = bcol0 + wc * 64 + n * 16 + rl;
        float bv = bias[col];
#pragma unroll
        for (int m = 0; m < 4; ++m) {
            int rowb = arow0 + wr * 64 + m * 16 + rg;
#pragma unroll
            for (int j = 0; j < 4; ++j)
                C[(size_t)(rowb + j) * N + col] = acc[m][n][j] + bv;
        }
    }
}

extern "C" void kernel_launch(void* const* d_in, const int* in_sizes, int n_in,
                              void* d_out, int out_size, void* d_ws, size_t ws_size,
                              hipStream_t stream) {
    const float* x = (const float*)d_in[0];     // [M,K]
    const float* w = (const float*)d_in[1];     // [N,K]
    const float* bias = (const float*)d_in[2];  // [N]
    float* out = (float*)d_out;

    const int N = in_sizes[2];                 // 16384
    const int K = in_sizes[1] / N;             // 4096
    const int M = in_sizes[0] / K;             // 8192

    unsigned char* xq = (unsigned char*)d_ws;          // M*K = 33.5 MB
    unsigned char* wq = xq + (size_t)M * K;            // N*K = 67 MB

    int nx8 = M * K / 8;
    int nw8 = N * K / 8;
    quant8<<<(nx8 + 255) / 256, 256, 0, stream>>>(
        (const float4*)x, (int2*)xq, nx8, 1.0f);
    quant8<<<(nw8 + 255) / 256, 256, 0, stream>>>(
        (const float4*)w, (int2*)wq, nw8, 64.0f);

    int nwg = (M / BM) * (N / BN);  // 64*128 = 8192, %8==0
    gemm_fp8<<<nwg, 256, 0, stream>>>(
        xq, wq, bias, out, M, N, K);
}

// Round 10
// 804.236 us; speedup vs baseline: 5.2766x; 1.1202x over previous
//
#include <hip/hip_runtime.h>
#include <hip/hip_bf16.h>

// FP8Linear: out = Xq @ Wq^T + bias. Reference quantize (scale=1) == RNE
// conversion to OCP e4m3fn; x stored as e4m3(x); w stored as e4m3(w*2^6)
// with MFMA B-scale 2^-6 (e8m0 0x79) so all |w|>=2^-12 quantize EXACTLY.
// GEMM R10: switch 16x16x128 -> mfma_scale_f32_32x32x64_f8f6f4.
// Rationale (R9 counters): m97-loop was LDS-read-bound (128KB frag reads +
// 32KB DMA per tile per block ~ 1250 port-cyc vs 553 MFMA cyc/SIMD;
// MfmaUtil ceiling ~50%, measured 31%). 32x32 doubles operand reuse per LDS
// byte: frag reads halve to 16KB/wave/tile -> LDS ~ balanced with MFMA.
// Everything else proven-in-place: 128x128 tile, BK=128, 4 waves (2x2,
// 64x64 each), single 32KB LDS buffer, 2-barrier loop, global_load_lds
// width 16 w/ pre-swizzled source, XOR-swizzled reads, XCD block swizzle.

typedef int i32x4 __attribute__((ext_vector_type(4)));
typedef int i32x8 __attribute__((ext_vector_type(8)));
typedef float f32x16 __attribute__((ext_vector_type(16)));

#define BM 128
#define BN 128
#define BK 128

// clip to +-448, scale (1 or 64), RNE-encode 8 f32 -> 8 e4m3 bytes.
__global__ __launch_bounds__(256) void quant8(
    const float4* __restrict__ in, int2* __restrict__ out, int n8, float scale) {
    int i = blockIdx.x * blockDim.x + threadIdx.x;
    if (i >= n8) return;
    float4 a = in[i * 2];
    float4 b = in[i * 2 + 1];
    float c0 = fminf(fmaxf(a.x, -448.f), 448.f) * scale;
    float c1 = fminf(fmaxf(a.y, -448.f), 448.f) * scale;
    float c2 = fminf(fmaxf(a.z, -448.f), 448.f) * scale;
    float c3 = fminf(fmaxf(a.w, -448.f), 448.f) * scale;
    float c4 = fminf(fmaxf(b.x, -448.f), 448.f) * scale;
    float c5 = fminf(fmaxf(b.y, -448.f), 448.f) * scale;
    float c6 = fminf(fmaxf(b.z, -448.f), 448.f) * scale;
    float c7 = fminf(fmaxf(b.w, -448.f), 448.f) * scale;
    int lo = __builtin_amdgcn_cvt_pk_fp8_f32(c0, c1, 0, false);
    lo = __builtin_amdgcn_cvt_pk_fp8_f32(c2, c3, lo, true);
    int hi = __builtin_amdgcn_cvt_pk_fp8_f32(c4, c5, 0, false);
    hi = __builtin_amdgcn_cvt_pk_fp8_f32(c6, c7, hi, true);
    out[i] = make_int2(lo, hi);
}

__device__ __forceinline__ void gload_lds16(const void* g, void* l) {
    __builtin_amdgcn_global_load_lds(
        (const __attribute__((address_space(1))) void*)g,
        (__attribute__((address_space(3))) void*)l,
        16, 0, 0);
}

// Read one lane's 32-byte k-block (logical byte cols [c0, c0+32)) of `row`
// from a swizzled [128 rows][128B] LDS tile. LDS[r][c] holds G[r][c ^ sw(r)],
// sw(r) = (r&7)<<4, so logical col cl lives at LDS col cl ^ sw(r).
__device__ __forceinline__ i32x8 frag32(const unsigned char* base, int row, int c0) {
    const int sw = (row & 7) << 4;
    const unsigned char* p = base + row * 128;
    i32x4 lo = *(const i32x4*)(p + (c0 ^ sw));
    i32x4 hi = *(const i32x4*)(p + ((c0 + 16) ^ sw));
    i32x8 r;
    r[0] = lo[0]; r[1] = lo[1]; r[2] = lo[2]; r[3] = lo[3];
    r[4] = hi[0]; r[5] = hi[1]; r[6] = hi[2]; r[7] = hi[3];
    return r;
}

// A: Xq8 [M][K] e4m3, B: Wq8 [N][K] e4m3 (pre-scaled by 2^6), C: [M][N] f32
__global__ __launch_bounds__(256, 2) void gemm_fp8(
    const unsigned char* __restrict__ A, const unsigned char* __restrict__ B,
    const float* __restrict__ bias, float* __restrict__ C,
    int M, int N, int K) {
    __shared__ unsigned char lA[BM * BK];  // 16 KB
    __shared__ unsigned char lB[BN * BK];  // 16 KB

    const int tid = threadIdx.x;
    const int lane = tid & 63;
    const int wave = tid >> 6;
    const int wr = wave >> 1;  // 2x2 wave grid, 64x64 output each
    const int wc = wave & 1;

    // XCD-aware bijective block swizzle (nwg % 8 == 0)
    const int nwg = gridDim.x;
    const int per = nwg >> 3;
    const int bid = blockIdx.x;
    const int wg = (bid & 7) * per + (bid >> 3);
    const int mtiles = M / BM;
    const int bm = wg % mtiles;
    const int bn = wg / mtiles;

    const int arow0 = bm * BM, bcol0 = bn * BN;
    const int NT = K / BK;  // 32

    const int rl = lane & 31;    // fragment row-within-32 (A row / B col)
    const int g2 = lane >> 5;    // k-half within one mfma's 64-byte k-range

    const unsigned char* const Ag = A + (size_t)arow0 * K;
    const unsigned char* const Bg = B + (size_t)bcol0 * K;

    // staging: thread t writes LDS bytes [t*16,(t+1)*16) of each 4KB chunk;
    // LDS dest linear (DMA constraint), global source pre-swizzled.
    const int srow = tid >> 3;                       // row within 32-row chunk
    const int ssrc_col = ((tid & 7) * 16) ^ (((tid >> 3) & 7) << 4);
    const int sdst = tid * 16;

    f32x16 acc[2][2] = {};

    for (int t = 0; t < NT; ++t) {
        const int kt = t * BK;
#pragma unroll
        for (int i = 0; i < 4; ++i)
            gload_lds16(Ag + (size_t)(i * 32 + srow) * K + kt + ssrc_col,
                        lA + i * 4096 + sdst);
#pragma unroll
        for (int i = 0; i < 4; ++i)
            gload_lds16(Bg + (size_t)(i * 32 + srow) * K + kt + ssrc_col,
                        lB + i * 4096 + sdst);
        __syncthreads();  // implicit vmcnt(0): tile landed, visible to all

#pragma unroll
        for (int ks = 0; ks < 2; ++ks) {
            const int c0 = ks * 64 + g2 * 32;
            i32x8 af[2], bf[2];
#pragma unroll
            for (int m = 0; m < 2; ++m)
                af[m] = frag32(lA, wr * 64 + m * 32 + rl, c0);
#pragma unroll
            for (int n = 0; n < 2; ++n)
                bf[n] = frag32(lB, wc * 64 + n * 32 + rl, c0);
#pragma unroll
            for (int m = 0; m < 2; ++m)
#pragma unroll
                for (int n = 0; n < 2; ++n)
                    acc[m][n] = __builtin_amdgcn_mfma_scale_f32_32x32x64_f8f6f4(
                        af[m], bf[n], acc[m][n],
                        0, 0,                 // cbsz=fp8(e4m3), blgp=fp8(e4m3)
                        0, 0x7F7F7F7F,        // A scale: 2^0
                        0, 0x79797979);       // B scale: 2^-6 (undo w*2^6)
        }
        __syncthreads();  // protect buffer before next tile's DMA
    }

    // epilogue: 32x32 C/D: col = lane&31, row = (reg&3)+8*(reg>>2)+4*(lane>>5)
#pragma unroll
    for (int n = 0; n < 2; ++n) {
        int col = bcol0 + wc * 64 + n * 32 + rl;
        float bv = bias[col];
#pragma unroll
        for (int m = 0; m < 2; ++m) {
            int rowb = arow0 + wr * 64 + m * 32 + g2 * 4;
#pragma unroll
            for (int reg = 0; reg < 16; ++reg) {
                int row = rowb + (reg & 3) + 8 * (reg >> 2);
                C[(size_t)row * N + col] = acc[m][n][reg] + bv;
            }
        }
    }
}

extern "C" void kernel_launch(void* const* d_in, const int* in_sizes, int n_in,
                              void* d_out, int out_size, void* d_ws, size_t ws_size,
                              hipStream_t stream) {
    const float* x = (const float*)d_in[0];     // [M,K]
    const float* w = (const float*)d_in[1];     // [N,K]
    const float* bias = (const float*)d_in[2];  // [N]
    float* out = (float*)d_out;

    const int N = in_sizes[2];                 // 16384
    const int K = in_sizes[1] / N;             // 4096
    const int M = in_sizes[0] / K;             // 8192

    unsigned char* xq = (unsigned char*)d_ws;          // M*K = 33.5 MB
    unsigned char* wq = xq + (size_t)M * K;            // N*K = 67 MB

    int nx8 = M * K / 8;
    int nw8 = N * K / 8;
    quant8<<<(nx8 + 255) / 256, 256, 0, stream>>>(
        (const float4*)x, (int2*)xq, nx8, 1.0f);
    quant8<<<(nw8 + 255) / 256, 256, 0, stream>>>(
        (const float4*)w, (int2*)wq, nw8, 64.0f);

    int nwg = (M / BM) * (N / BN);  // 64*128 = 8192, %8==0
    gemm_fp8<<<nwg, 256, 0, stream>>>(
        xq, wq, bias, out, M, N, K);
}

// Round 11
// 795.748 us; speedup vs baseline: 5.3329x; 1.0107x over previous
//
#include <hip/hip_runtime.h>
#include <hip/hip_bf16.h>

// FP8Linear: out = Xq @ Wq^T + bias. Reference quantize (scale=1) == RNE
// conversion to OCP e4m3fn; x stored as e4m3(x); w stored as e4m3(w*2^6)
// with MFMA B-scale 2^-6 (e8m0 0x79) so all |w|>=2^-12 quantize EXACTLY.
// GEMM R11: 256x256 tile, BK=128, 8 waves (2Mx4N, 128x64 out each),
// double-buffered 128KB LDS, ONE __syncthreads per K-tile, DMA issued a
// full tile ahead (drain cheap: ~2000cyc issue->drain >> 900cyc latency).
// Rationale (R10 counters + calibrated model): LDS-port floor was binding
// (25GB -> 320us > 235us MFMA floor; MfmaUtil 31% == 235/712 exactly).
// 2x MN-tile raises LDS reuse 1.5x (16.8GB -> 213us < MFMA floor) and
// dbuf removes the single-buffer DMA drain. mfma_scale_f32_32x32x64_f8f6f4,
// global_load_lds w/ pre-swizzled source, XOR-swizzled reads, XCD swizzle.

typedef int i32x4 __attribute__((ext_vector_type(4)));
typedef int i32x8 __attribute__((ext_vector_type(8)));
typedef float f32x16 __attribute__((ext_vector_type(16)));

#define BM 256
#define BN 256
#define BK 128

// clip to +-448, scale (1 or 64), RNE-encode 8 f32 -> 8 e4m3 bytes.
__global__ __launch_bounds__(256) void quant8(
    const float4* __restrict__ in, int2* __restrict__ out, int n8, float scale) {
    int i = blockIdx.x * blockDim.x + threadIdx.x;
    if (i >= n8) return;
    float4 a = in[i * 2];
    float4 b = in[i * 2 + 1];
    float c0 = fminf(fmaxf(a.x, -448.f), 448.f) * scale;
    float c1 = fminf(fmaxf(a.y, -448.f), 448.f) * scale;
    float c2 = fminf(fmaxf(a.z, -448.f), 448.f) * scale;
    float c3 = fminf(fmaxf(a.w, -448.f), 448.f) * scale;
    float c4 = fminf(fmaxf(b.x, -448.f), 448.f) * scale;
    float c5 = fminf(fmaxf(b.y, -448.f), 448.f) * scale;
    float c6 = fminf(fmaxf(b.z, -448.f), 448.f) * scale;
    float c7 = fminf(fmaxf(b.w, -448.f), 448.f) * scale;
    int lo = __builtin_amdgcn_cvt_pk_fp8_f32(c0, c1, 0, false);
    lo = __builtin_amdgcn_cvt_pk_fp8_f32(c2, c3, lo, true);
    int hi = __builtin_amdgcn_cvt_pk_fp8_f32(c4, c5, 0, false);
    hi = __builtin_amdgcn_cvt_pk_fp8_f32(c6, c7, hi, true);
    out[i] = make_int2(lo, hi);
}

__device__ __forceinline__ void gload_lds16(const void* g, void* l) {
    __builtin_amdgcn_global_load_lds(
        (const __attribute__((address_space(1))) void*)g,
        (__attribute__((address_space(3))) void*)l,
        16, 0, 0);
}

// Read one lane's 32-byte k-block (logical byte cols [c0, c0+32)) of `row`
// from a swizzled [rows][128B] LDS tile. LDS[r][c] holds G[r][c ^ sw(r)],
// sw(r) = (r&7)<<4, so logical col cl lives at LDS col cl ^ sw(r).
__device__ __forceinline__ i32x8 frag32(const unsigned char* base, int row, int c0) {
    const int sw = (row & 7) << 4;
    const unsigned char* p = base + row * 128;
    i32x4 lo = *(const i32x4*)(p + (c0 ^ sw));
    i32x4 hi = *(const i32x4*)(p + ((c0 + 16) ^ sw));
    i32x8 r;
    r[0] = lo[0]; r[1] = lo[1]; r[2] = lo[2]; r[3] = lo[3];
    r[4] = hi[0]; r[5] = hi[1]; r[6] = hi[2]; r[7] = hi[3];
    return r;
}

// A: Xq8 [M][K] e4m3, B: Wq8 [N][K] e4m3 (pre-scaled by 2^6), C: [M][N] f32
__global__ __launch_bounds__(512, 1) void gemm_fp8(
    const unsigned char* __restrict__ A, const unsigned char* __restrict__ B,
    const float* __restrict__ bias, float* __restrict__ C,
    int M, int N, int K) {
    extern __shared__ unsigned char lds[];
    // buf0: A [0,32K) B [32K,64K); buf1: A [64K,96K) B [96K,128K)

    const int tid = threadIdx.x;
    const int lane = tid & 63;
    const int wave = tid >> 6;
    const int wr = wave >> 2;   // 0..1 -> 128 A-rows each
    const int wc = wave & 3;    // 0..3 -> 64 B-cols each

    // XCD-aware bijective block swizzle (nwg % 8 == 0)
    const int nwg = gridDim.x;
    const int per = nwg >> 3;
    const int bid = blockIdx.x;
    const int wg = (bid & 7) * per + (bid >> 3);
    const int mtiles = M / BM;
    const int bm = wg % mtiles;
    const int bn = wg / mtiles;

    const int arow0 = bm * BM, bcol0 = bn * BN;
    const int NT = K / BK;  // 32

    const int rl = lane & 31;    // fragment row-within-32 (A row / B col)
    const int g2 = lane >> 5;    // k-half selector within 64-byte mfma k-range

    const unsigned char* const Ag = A + (size_t)arow0 * K;
    const unsigned char* const Bg = B + (size_t)bcol0 * K;

    // staging (per 32KB region = 256 rows x 128B): thread t, chunk c:
    // dst byte = c*8192 + t*16 (linear, DMA constraint)
    // -> row = c*64 + (t>>3), logical col = (t&7)*16, src col pre-swizzled.
    const int srow = tid >> 3;                       // 0..63
    const int ssrc_col = ((tid & 7) * 16) ^ (((tid >> 3) & 7) << 4);
    const int sdst = tid * 16;

    auto stage = [&](const unsigned char* Gp, unsigned char* Lp, int kt) {
#pragma unroll
        for (int c = 0; c < 4; ++c)
            gload_lds16(Gp + (size_t)(c * 64 + srow) * K + kt + ssrc_col,
                        Lp + c * 8192 + sdst);
    };

    f32x16 acc[4][2] = {};

    // ---- prologue: tile 0 -> buf0
    stage(Ag, lds, 0);
    stage(Bg, lds + 32768, 0);
    __syncthreads();  // implicit vmcnt(0): tile 0 landed

    for (int t = 0; t < NT; ++t) {
        const int cur = t & 1;
        const unsigned char* Ab = lds + cur * 65536;
        const unsigned char* Bb = Ab + 32768;
        unsigned char* Anx = lds + (cur ^ 1) * 65536;

        // issue next tile's DMAs first: a full tile of latency cover
        if (t + 1 < NT) {
            stage(Ag, Anx, (t + 1) * BK);
            stage(Bg, Anx + 32768, (t + 1) * BK);
        }

#pragma unroll
        for (int ks = 0; ks < 2; ++ks) {
            const int c0 = ks * 64 + g2 * 32;
            i32x8 af[4], bf[2];
#pragma unroll
            for (int n = 0; n < 2; ++n)
                bf[n] = frag32(Bb, wc * 64 + n * 32 + rl, c0);
#pragma unroll
            for (int m = 0; m < 4; ++m)
                af[m] = frag32(Ab, wr * 128 + m * 32 + rl, c0);
#pragma unroll
            for (int m = 0; m < 4; ++m)
#pragma unroll
                for (int n = 0; n < 2; ++n)
                    acc[m][n] = __builtin_amdgcn_mfma_scale_f32_32x32x64_f8f6f4(
                        af[m], bf[n], acc[m][n],
                        0, 0,                 // cbsz=fp8(e4m3), blgp=fp8(e4m3)
                        0, 0x7F7F7F7F,        // A scale: 2^0
                        0, 0x79797979);       // B scale: 2^-6 (undo w*2^6)
        }

        // one sync/tile: drains this iteration's DMAs (issued ~2000cyc ago,
        // already landed) + publishes buffers; protects both dbuf halves.
        __syncthreads();
    }

    // epilogue: 32x32 C/D: col = lane&31, row = (reg&3)+8*(reg>>2)+4*(lane>>5)
#pragma unroll
    for (int n = 0; n < 2; ++n) {
        int col = bcol0 + wc * 64 + n * 32 + rl;
        float bv = bias[col];
#pragma unroll
        for (int m = 0; m < 4; ++m) {
            int rowb = arow0 + wr * 128 + m * 32 + g2 * 4;
#pragma unroll
            for (int reg = 0; reg < 16; ++reg) {
                int row = rowb + (reg & 3) + 8 * (reg >> 2);
                C[(size_t)row * N + col] = acc[m][n][reg] + bv;
            }
        }
    }
}

extern "C" void kernel_launch(void* const* d_in, const int* in_sizes, int n_in,
                              void* d_out, int out_size, void* d_ws, size_t ws_size,
                              hipStream_t stream) {
    const float* x = (const float*)d_in[0];     // [M,K]
    const float* w = (const float*)d_in[1];     // [N,K]
    const float* bias = (const float*)d_in[2];  // [N]
    float* out = (float*)d_out;

    const int N = in_sizes[2];                 // 16384
    const int K = in_sizes[1] / N;             // 4096
    const int M = in_sizes[0] / K;             // 8192

    unsigned char* xq = (unsigned char*)d_ws;          // M*K = 33.5 MB
    unsigned char* wq = xq + (size_t)M * K;            // N*K = 67 MB

    int nx8 = M * K / 8;
    int nw8 = N * K / 8;
    quant8<<<(nx8 + 255) / 256, 256, 0, stream>>>(
        (const float4*)x, (int2*)xq, nx8, 1.0f);
    quant8<<<(nw8 + 255) / 256, 256, 0, stream>>>(
        (const float4*)w, (int2*)wq, nw8, 64.0f);

    hipFuncSetAttribute((const void*)gemm_fp8,
                        hipFuncAttributeMaxDynamicSharedMemorySize, 131072);

    int nwg = (M / BM) * (N / BN);  // 32*64 = 2048, %8==0
    gemm_fp8<<<nwg, 512, 131072, stream>>>(
        xq, wq, bias, out, M, N, K);
}